// Round 6
// baseline (326.733 us; speedup 1.0000x reference)
//
#include <hip/hip_runtime.h>

// Capsule dynamic routing — LDS-staged weights, 2 batch elems per thread.
// u_i:(B,N,DI) f32, w:(1,N,NO,DI,DE) f32, bias:(N,NO,1) f32, r=3.
// Identity: logits_r = u_ji . vsum  (vsum = running sum of v over iters;
// u_ji includes bias so the bias*sum_e term folds in automatically).
// routing: per block = (8-n tile) x (32 b); w tile staged to LDS in 2-n
// chunks, double-buffered; each thread owns (2 b, 5 o, 4 e) and loops n.
// squash: 4-way tile split per element + shuffle combine.

#define B    256
#define N    1152
#define NO   10
#define DI   8
#define DE   16
#define NTILE   8
#define NTILES  144    // N / NTILE
#define CHUNK   2
#define NCHUNK  4      // NTILE / CHUNK
#define BTILE   32
#define BTILES  8
#define THREADS 128
#define WFLT    (NO * DI * DE)     // 1280 floats per n
#define CHUNKF  (CHUNK * WFLT)     // 2560 floats (10 KB)
#define CHUNKV4 (CHUNKF / 4)       // 640 float4 slots

// ws layout (floats) — 23.76 MB total (same as round 5)
#define SP_OFF 0
#define SP_SZ  (NTILES * B * NO * DE)   // 5,898,240
#define VS_OFF (SP_OFF + SP_SZ)
#define VS_SZ  (B * NO * DE)            // 40,960

// ---------------------------------------------------------------------------
// Routing pass. Lane bits: e4 = lane&3, oh = (lane>>2)&1, bb = wv*8 + lane>>3.
// Thread owns b0 = base+bb and b1 = b0+16; 5 o (oh half); e-quad e4.
// Grid: 144 n-tiles x 8 b-tiles = 1152 blocks x 2 waves.
// ---------------------------------------------------------------------------
__global__ __launch_bounds__(THREADS, 3)
void routing_kernel(const float* __restrict__ u,
                    const float* __restrict__ w,
                    const float* __restrict__ bias,
                    const float* __restrict__ vsum,
                    float* __restrict__ s_part,
                    const int has_v) {
    __shared__ float lds_w[2][CHUNKF];          // 20 KB
    const int tid   = threadIdx.x;
    const int lane  = tid & 63;
    const int e4    = lane & 3;
    const int oh    = (lane >> 2) & 1;
    const int bb    = (tid >> 6) * 8 + (lane >> 3);
    const int b0    = blockIdx.y * BTILE + bb;
    const int b1    = b0 + 16;
    const int n0    = blockIdx.x * NTILE;
    const int obase = oh * 5;

    // vsum fragments (loop-invariant), dense float4 from (B,NO,DE)
    float4 vva[5], vvb[5];
#pragma unroll
    for (int ok = 0; ok < 5; ++ok) {
        vva[ok] = make_float4(0.f, 0.f, 0.f, 0.f);
        vvb[ok] = vva[ok];
    }
    if (has_v) {
#pragma unroll
        for (int ok = 0; ok < 5; ++ok) {
            vva[ok] = *(const float4*)(vsum + ((size_t)b0 * NO + obase + ok) * DE + e4 * 4);
            vvb[ok] = *(const float4*)(vsum + ((size_t)b1 * NO + obase + ok) * DE + e4 * 4);
        }
    }

    float4 acca[5], accb[5];
#pragma unroll
    for (int ok = 0; ok < 5; ++ok) {
        acca[ok] = make_float4(0.f, 0.f, 0.f, 0.f);
        accb[ok] = acca[ok];
    }

    // --- stage chunk 0 ---
    const float4* wsrc = (const float4*)(w + (size_t)n0 * WFLT);
    float4 stg[5];
#pragma unroll
    for (int j = 0; j < 5; ++j) stg[j] = wsrc[tid + j * THREADS];
#pragma unroll
    for (int j = 0; j < 5; ++j) ((float4*)lds_w[0])[tid + j * THREADS] = stg[j];
    __syncthreads();

    for (int k = 0; k < NCHUNK; ++k) {
        // prefetch next chunk into registers (VMEM overlaps compute below)
        if (k + 1 < NCHUNK) {
            const float4* src2 = wsrc + (size_t)(k + 1) * CHUNKV4;
#pragma unroll
            for (int j = 0; j < 5; ++j) stg[j] = src2[tid + j * THREADS];
        }

        const float* lw = lds_w[k & 1];
#pragma unroll
        for (int i = 0; i < CHUNK; ++i) {
            const int n = n0 + k * CHUNK + i;
            const float* upa = u + ((size_t)b0 * N + n) * DI;
            const float* upb = u + ((size_t)b1 * N + n) * DI;
            const float4 a0 = *(const float4*)upa, a1 = *(const float4*)(upa + 4);
            const float4 g0 = *(const float4*)upb, g1 = *(const float4*)(upb + 4);
            const float ura[DI] = {a0.x, a0.y, a0.z, a0.w, a1.x, a1.y, a1.z, a1.w};
            const float urb[DI] = {g0.x, g0.y, g0.z, g0.w, g1.x, g1.y, g1.z, g1.w};

            const float* lwn = lw + i * WFLT + obase * (DI * DE) + e4 * 4;
            float4 ujia[5], ujib[5];
#pragma unroll
            for (int ok = 0; ok < 5; ++ok) {
                const float bv = bias[n * NO + obase + ok];
                float4 pa = make_float4(bv, bv, bv, bv);
                float4 pb = pa;
                const float* wo = lwn + ok * (DI * DE);
#pragma unroll
                for (int d = 0; d < DI; ++d) {
                    const float4 w4 = *(const float4*)(wo + d * DE);
                    pa.x += ura[d] * w4.x; pa.y += ura[d] * w4.y;
                    pa.z += ura[d] * w4.z; pa.w += ura[d] * w4.w;
                    pb.x += urb[d] * w4.x; pb.y += urb[d] * w4.y;
                    pb.z += urb[d] * w4.z; pb.w += urb[d] * w4.w;
                }
                ujia[ok] = pa; ujib[ok] = pb;
            }

            float ca[5], cb[5];
            if (has_v) {
                float lga[5], lgb[5];
#pragma unroll
                for (int ok = 0; ok < 5; ++ok) {
                    float da = ujia[ok].x * vva[ok].x + ujia[ok].y * vva[ok].y
                             + ujia[ok].z * vva[ok].z + ujia[ok].w * vva[ok].w;
                    float db = ujib[ok].x * vvb[ok].x + ujib[ok].y * vvb[ok].y
                             + ujib[ok].z * vvb[ok].z + ujib[ok].w * vvb[ok].w;
                    da += __shfl_xor(da, 1); da += __shfl_xor(da, 2);
                    db += __shfl_xor(db, 1); db += __shfl_xor(db, 2);
                    lga[ok] = da; lgb[ok] = db;
                }
                // softmax over 10 o: 5 local + exchange with other o-half (xor 4)
                float ma = lga[0], mb = lgb[0];
#pragma unroll
                for (int ok = 1; ok < 5; ++ok) { ma = fmaxf(ma, lga[ok]); mb = fmaxf(mb, lgb[ok]); }
                ma = fmaxf(ma, __shfl_xor(ma, 4));
                mb = fmaxf(mb, __shfl_xor(mb, 4));
                float sa = 0.f, sb = 0.f;
#pragma unroll
                for (int ok = 0; ok < 5; ++ok) {
                    ca[ok] = __expf(lga[ok] - ma); sa += ca[ok];
                    cb[ok] = __expf(lgb[ok] - mb); sb += cb[ok];
                }
                sa += __shfl_xor(sa, 4);
                sb += __shfl_xor(sb, 4);
                const float ia = 1.f / sa, ib = 1.f / sb;
#pragma unroll
                for (int ok = 0; ok < 5; ++ok) { ca[ok] *= ia; cb[ok] *= ib; }
            } else {
#pragma unroll
                for (int ok = 0; ok < 5; ++ok) { ca[ok] = 0.1f; cb[ok] = 0.1f; }
            }

#pragma unroll
            for (int ok = 0; ok < 5; ++ok) {
                acca[ok].x += ca[ok] * ujia[ok].x; acca[ok].y += ca[ok] * ujia[ok].y;
                acca[ok].z += ca[ok] * ujia[ok].z; acca[ok].w += ca[ok] * ujia[ok].w;
                accb[ok].x += cb[ok] * ujib[ok].x; accb[ok].y += cb[ok] * ujib[ok].y;
                accb[ok].z += cb[ok] * ujib[ok].z; accb[ok].w += cb[ok] * ujib[ok].w;
            }
        }

        // commit prefetched chunk to the other LDS buffer
        if (k + 1 < NCHUNK) {
#pragma unroll
            for (int j = 0; j < 5; ++j)
                ((float4*)lds_w[(k + 1) & 1])[tid + j * THREADS] = stg[j];
        }
        __syncthreads();
    }

    // deterministic per-tile partials: s_part[tile][b][o][e]
    float* spa = s_part + (((size_t)blockIdx.x * B + b0) * NO + obase) * DE + e4 * 4;
    float* spb = s_part + (((size_t)blockIdx.x * B + b1) * NO + obase) * DE + e4 * 4;
#pragma unroll
    for (int ok = 0; ok < 5; ++ok) {
        *(float4*)(spa + ok * DE) = acca[ok];
        *(float4*)(spb + ok * DE) = accb[ok];
    }
}

// ---------------------------------------------------------------------------
// Squash: s = sum_tiles s_part; v = ||s||/(1+||s||^2)*s; out = v; vsum += v.
// 4 threads per element (36 tiles each) -> 4x parallelism vs round 5.
// t0 bits: q = t0&3 (tile quarter), g = t0>>2 = (b*NO+o)*16 + e.
// Wave = 4 q x 16 e of one (b,o): combine q via xor(1,2), norm via xor(4..32).
// ---------------------------------------------------------------------------
__global__ __launch_bounds__(256)
void squash_kernel(const float* __restrict__ s_part,
                   float* __restrict__ vsum,
                   float* __restrict__ out,
                   const int accum) {
    const int t0 = blockIdx.x * 256 + threadIdx.x;   // < 4*40960
    const int q  = t0 & 3;
    const int g  = t0 >> 2;

    float s = 0.f;
    const float* sp = s_part + (size_t)(q * 36) * (B * NO * DE) + g;
#pragma unroll 9
    for (int i = 0; i < 36; ++i)
        s += sp[(size_t)i * (B * NO * DE)];
    s += __shfl_xor(s, 1);
    s += __shfl_xor(s, 2);        // full tile sum, all q lanes

    float nsq = s * s;
#pragma unroll
    for (int msk = 4; msk <= 32; msk <<= 1) nsq += __shfl_xor(nsq, msk);
    const float nrm   = sqrtf(nsq);
    const float scale = nrm / (1.f + nsq);
    const float val   = s * scale;

    if (q == 0) {
        out[g]  = val;                               // (B,NO,DE)
        vsum[g] = accum ? (vsum[g] + val) : val;
    }
}

extern "C" void kernel_launch(void* const* d_in, const int* in_sizes, int n_in,
                              void* d_out, int out_size, void* d_ws, size_t ws_size,
                              hipStream_t stream) {
    const float* u    = (const float*)d_in[0];
    const float* w    = (const float*)d_in[1];   // (N,NO,DI,DE)
    const float* bias = (const float*)d_in[2];   // (N,NO)
    // d_in[3] = r, static 3

    float* wsf    = (float*)d_ws;
    float* s_part = wsf + SP_OFF;
    float* vsum   = wsf + VS_OFF;
    float* out    = (float*)d_out;

    for (int it = 0; it < 3; ++it) {
        routing_kernel<<<dim3(NTILES, BTILES), THREADS, 0, stream>>>(
            u, w, bias, vsum, s_part, it > 0);
        squash_kernel<<<(4 * B * NO * DE) / 256, 256, 0, stream>>>(
            s_part, vsum, out, it > 0);
    }
}

// Round 7
// 195.134 us; speedup vs baseline: 1.6744x; 1.6744x over previous
//
#include <hip/hip_runtime.h>

// Capsule dynamic routing — b-on-lanes / o-on-waves, wave-uniform weights.
// u_i:(B,N,DI) f32, w:(1,N,NO,DI,DE) f32, bias:(N,NO,1) f32, r=3.
// Identity: logits_r = u_ji . vsum (vsum = running sum of v; u_ji includes
// bias so the bias term folds in).
// routing block = 5 waves x 64 lanes; wave wv owns o in {2wv,2wv+1}; lane = b.
// Weight/bias addresses are wave-uniform (readfirstlane) -> scalar-load path,
// zero lane redundancy. Full 16-e per thread -> logits dot + acc in-thread,
// no shuffles. Softmax over 10 o via 2.5 KB LDS exchange per n.
// Register budget ~140 (< 168 cap at launch_bounds(320,3)) -- no spill (R6 bug).

#define B    256
#define N    1152
#define NO   10
#define DI   8
#define DE   16
#define NTILE   8
#define NTILES  144    // N / NTILE
#define BG      64     // b per block (= lanes per wave)
#define BGS     4      // B / BG
#define THREADS 320    // 5 waves

// ws layout (floats) — same 23.76 MB as rounds 5/6
#define SP_OFF 0
#define SP_SZ  (NTILES * B * NO * DE)   // 5,898,240
#define VS_OFF (SP_OFF + SP_SZ)
#define VS_SZ  (B * NO * DE)            // 40,960

// ---------------------------------------------------------------------------
// Routing pass. Grid: (144 n-tiles, 4 b-groups) x 320 threads.
// ---------------------------------------------------------------------------
__global__ __launch_bounds__(THREADS, 3)
void routing_kernel(const float* __restrict__ u,
                    const float* __restrict__ w,
                    const float* __restrict__ bias,
                    const float* __restrict__ vsum,
                    float* __restrict__ s_part,
                    const int has_v) {
    __shared__ float lgx[NO][BG];               // 2.5 KB logit exchange
    const int tid  = threadIdx.x;
    const int lane = tid & 63;
    const int wv   = __builtin_amdgcn_readfirstlane(tid >> 6);  // 0..4, uniform
    const int o0   = wv * 2;
    const int b    = blockIdx.y * BG + lane;
    const int n0   = blockIdx.x * NTILE;

    // vsum fragment for this thread's (b, o0..o0+1), full e — loop-invariant
    float4 vv[2][4];
#pragma unroll
    for (int oi = 0; oi < 2; ++oi)
#pragma unroll
        for (int eq = 0; eq < 4; ++eq)
            vv[oi][eq] = make_float4(0.f, 0.f, 0.f, 0.f);
    if (has_v) {
#pragma unroll
        for (int oi = 0; oi < 2; ++oi)
#pragma unroll
            for (int eq = 0; eq < 4; ++eq)
                vv[oi][eq] = *(const float4*)(vsum + ((size_t)b * NO + o0 + oi) * DE + eq * 4);
    }

    float4 acc[2][4];
#pragma unroll
    for (int oi = 0; oi < 2; ++oi)
#pragma unroll
        for (int eq = 0; eq < 4; ++eq)
            acc[oi][eq] = make_float4(0.f, 0.f, 0.f, 0.f);

    for (int i = 0; i < NTILE; ++i) {
        const int n = n0 + i;

        // u row for lane's b: 2x float4 (lanes scatter over b — L1-served)
        const float* up = u + ((size_t)b * N + n) * DI;
        const float4 u0 = *(const float4*)up;
        const float4 u1 = *(const float4*)(up + 4);
        const float ur[DI] = {u0.x, u0.y, u0.z, u0.w, u1.x, u1.y, u1.z, u1.w};

        // u_ji for (o0, o0+1), all 16 e — weight addrs wave-uniform
        const float* wp = w + ((size_t)n * NO + o0) * (DI * DE);
        float4 uji[2][4];
#pragma unroll
        for (int oi = 0; oi < 2; ++oi) {
            const float bv = bias[n * NO + o0 + oi];
#pragma unroll
            for (int eq = 0; eq < 4; ++eq)
                uji[oi][eq] = make_float4(bv, bv, bv, bv);
#pragma unroll
            for (int d = 0; d < DI; ++d) {
                const float* wrow = wp + oi * (DI * DE) + d * DE;
#pragma unroll
                for (int eq = 0; eq < 4; ++eq) {
                    const float4 w4 = *(const float4*)(wrow + eq * 4);
                    uji[oi][eq].x += ur[d] * w4.x;
                    uji[oi][eq].y += ur[d] * w4.y;
                    uji[oi][eq].z += ur[d] * w4.z;
                    uji[oi][eq].w += ur[d] * w4.w;
                }
            }
        }

        float c[2];
        if (has_v) {
            // logits: full-e dot in-thread, exchange via LDS for the softmax
#pragma unroll
            for (int oi = 0; oi < 2; ++oi) {
                float lg = 0.f;
#pragma unroll
                for (int eq = 0; eq < 4; ++eq)
                    lg += uji[oi][eq].x * vv[oi][eq].x + uji[oi][eq].y * vv[oi][eq].y
                        + uji[oi][eq].z * vv[oi][eq].z + uji[oi][eq].w * vv[oi][eq].w;
                lgx[o0 + oi][lane] = lg;
            }
            __syncthreads();
            float l[NO];
#pragma unroll
            for (int o = 0; o < NO; ++o) l[o] = lgx[o][lane];
            __syncthreads();   // reads done before next n overwrites

            float m = l[0];
#pragma unroll
            for (int o = 1; o < NO; ++o) m = fmaxf(m, l[o]);
            float sum = 0.f;
#pragma unroll
            for (int o = 0; o < NO; ++o) { l[o] = __expf(l[o] - m); sum += l[o]; }
            const float inv = 1.f / sum;
            c[0] = l[o0] * inv;
            c[1] = l[o0 + 1] * inv;
        } else {
            c[0] = 0.1f; c[1] = 0.1f;   // softmax of zeros
        }

#pragma unroll
        for (int oi = 0; oi < 2; ++oi)
#pragma unroll
            for (int eq = 0; eq < 4; ++eq) {
                acc[oi][eq].x += c[oi] * uji[oi][eq].x;
                acc[oi][eq].y += c[oi] * uji[oi][eq].y;
                acc[oi][eq].z += c[oi] * uji[oi][eq].z;
                acc[oi][eq].w += c[oi] * uji[oi][eq].w;
            }
    }

    // s_part[tile][b][o][e] — same layout squash already expects
    float* sp = s_part + (((size_t)blockIdx.x * B + b) * NO + o0) * DE;
#pragma unroll
    for (int oi = 0; oi < 2; ++oi)
#pragma unroll
        for (int eq = 0; eq < 4; ++eq)
            *(float4*)(sp + oi * DE + eq * 4) = acc[oi][eq];
}

// ---------------------------------------------------------------------------
// Squash (unchanged from round 6 — proven): s = sum_tiles s_part;
// v = ||s||/(1+||s||^2)*s; out = v; vsum += v. 4 threads/element (36 tiles ea).
// t0: q = t0&3 (tile quarter), g = t0>>2 = (b*NO+o)*16 + e.
// ---------------------------------------------------------------------------
__global__ __launch_bounds__(256)
void squash_kernel(const float* __restrict__ s_part,
                   float* __restrict__ vsum,
                   float* __restrict__ out,
                   const int accum) {
    const int t0 = blockIdx.x * 256 + threadIdx.x;   // < 4*40960
    const int q  = t0 & 3;
    const int g  = t0 >> 2;

    float s = 0.f;
    const float* sp = s_part + (size_t)(q * 36) * (B * NO * DE) + g;
#pragma unroll 9
    for (int i = 0; i < 36; ++i)
        s += sp[(size_t)i * (B * NO * DE)];
    s += __shfl_xor(s, 1);
    s += __shfl_xor(s, 2);        // full tile sum, all q lanes

    float nsq = s * s;
#pragma unroll
    for (int msk = 4; msk <= 32; msk <<= 1) nsq += __shfl_xor(nsq, msk);
    const float nrm   = sqrtf(nsq);
    const float scale = nrm / (1.f + nsq);
    const float val   = s * scale;

    if (q == 0) {
        out[g]  = val;                               // (B,NO,DE)
        vsum[g] = accum ? (vsum[g] + val) : val;
    }
}

extern "C" void kernel_launch(void* const* d_in, const int* in_sizes, int n_in,
                              void* d_out, int out_size, void* d_ws, size_t ws_size,
                              hipStream_t stream) {
    const float* u    = (const float*)d_in[0];
    const float* w    = (const float*)d_in[1];   // (N,NO,DI,DE)
    const float* bias = (const float*)d_in[2];   // (N,NO)
    // d_in[3] = r, static 3

    float* wsf    = (float*)d_ws;
    float* s_part = wsf + SP_OFF;
    float* vsum   = wsf + VS_OFF;
    float* out    = (float*)d_out;

    for (int it = 0; it < 3; ++it) {
        routing_kernel<<<dim3(NTILES, BGS), THREADS, 0, stream>>>(
            u, w, bias, vsum, s_part, it > 0);
        squash_kernel<<<(4 * B * NO * DE) / 256, 256, 0, stream>>>(
            s_part, vsum, out, it > 0);
    }
}